// Round 1
// baseline (481.162 us; speedup 1.0000x reference)
//
#include <hip/hip_runtime.h>

namespace {
constexpr int HD = 2;
constexpr int T  = 4;
constexpr int C  = 16;
constexpr int H  = 96;
constexpr int W  = 96;
constexpr int K  = 10;
constexpr int PS = 7;
constexpr int HW = H * W;              // 9216
constexpr int NPIX = T * HW;           // 36864 pixels per hd
constexpr int PATCH = PS * PS;         // 49
constexpr int OUTPIX = C * PATCH;      // 784 floats per pixel
constexpr int CHUNKS = 8;
constexpr int PIX_PER_CHUNK = NPIX / CHUNKS; // 4608
constexpr int BLOCK = 1024;
constexpr int GROUPS = BLOCK / 16;     // 64 pixel-groups per block
constexpr int ITERS = PIX_PER_CHUNK / GROUPS; // 72
}

__global__ __launch_bounds__(BLOCK, 1)
void wpsum_kernel(const float* __restrict__ vid,
                  const float* __restrict__ dists,
                  const int* __restrict__ inds,
                  float* __restrict__ out)
{
    // One (hd, c) slice of the video: vid[0, hd, :, c, :, :]  -> 144 KiB
    __shared__ float s_vid[NPIX];

    const int bid   = blockIdx.x;
    const int chunk = bid & (CHUNKS - 1);        // 8 chunks
    const int c     = (bid >> 3) & (C - 1);      // 16 channels
    const int hd    = bid >> 7;                  // 2 heads

    // ---- stage the (hd, c) slice into LDS: T contiguous planes of HW floats ----
    for (int t = 0; t < T; ++t) {
        const float4* g4 = reinterpret_cast<const float4*>(
            vid + (size_t)((hd * T + t) * C + c) * HW);
        float4* l4 = reinterpret_cast<float4*>(s_vid + t * HW);
        for (int idx = threadIdx.x; idx < HW / 4; idx += BLOCK)
            l4[idx] = g4[idx];
    }
    __syncthreads();

    const int tid = threadIdx.x;
    const int g   = tid >> 4;        // pixel-group within block (0..63)
    const int l   = tid & 15;        // lane within group

    // Each lane owns output elements f0,f1,f2 (and lane 0 also f=48)
    const int f0 = l, f1 = l + 16, f2 = l + 32;
    const int i0 = f0 / 7, j0 = f0 % 7;
    const int i1 = f1 / 7, j1 = f1 % 7;
    const int i2 = f2 / 7, j2 = f2 % 7;
    const int w0 = i0 * W + j0;
    const int w1 = i1 * W + j1;
    const int w2 = i2 * W + j2;
    constexpr int w3 = 6 * W + 6;    // f = 48 -> (i=6, j=6)
    const bool lead = (l == 0);

    const float* dbase = dists + (size_t)hd * NPIX * K;
    const int*   ibase = inds  + (size_t)hd * NPIX * K * 3;
    float*       obase = out   + (size_t)hd * NPIX * OUTPIX + (size_t)c * PATCH;

    const int pix0 = chunk * PIX_PER_CHUNK + g;

    for (int itr = 0; itr < ITERS; ++itr) {
        const int p = pix0 + itr * GROUPS;
        const float* dp = dbase + (size_t)p * K;
        const int*   ip = ibase + (size_t)p * (K * 3);

        float a0 = 0.f, a1 = 0.f, a2 = 0.f, a3 = 0.f;

#pragma unroll
        for (int k = 0; k < K; ++k) {
            const float d  = dp[k];
            const int   tt = ip[3 * k + 0];   // in [0,T): reflect(tt) == tt
            const int   ir = ip[3 * k + 1];
            const int   ic = ip[3 * k + 2];
            const int   tb = tt * HW;

            if (ir <= H - PS && ic <= W - PS) {
                // fast path: patch fully interior, addresses = base + const offset
                const int b0 = tb + ir * W + ic;
                a0 += d * s_vid[b0 + w0];
                a1 += d * s_vid[b0 + w1];
                a2 += d * s_vid[b0 + w2];
                if (lead) a3 += d * s_vid[b0 + w3];
            } else {
                // slow path: reflect each coordinate
                int rr, cc;
                rr = ir + i0; if (rr > H - 1) rr = 2 * (H - 1) - rr;
                cc = ic + j0; if (cc > W - 1) cc = 2 * (W - 1) - cc;
                a0 += d * s_vid[tb + rr * W + cc];

                rr = ir + i1; if (rr > H - 1) rr = 2 * (H - 1) - rr;
                cc = ic + j1; if (cc > W - 1) cc = 2 * (W - 1) - cc;
                a1 += d * s_vid[tb + rr * W + cc];

                rr = ir + i2; if (rr > H - 1) rr = 2 * (H - 1) - rr;
                cc = ic + j2; if (cc > W - 1) cc = 2 * (W - 1) - cc;
                a2 += d * s_vid[tb + rr * W + cc];

                if (lead) {
                    rr = ir + 6; if (rr > H - 1) rr = 2 * (H - 1) - rr;
                    cc = ic + 6; if (cc > W - 1) cc = 2 * (W - 1) - cc;
                    a3 += d * s_vid[tb + rr * W + cc];
                }
            }
        }

        float* op = obase + (size_t)p * OUTPIX;
        op[f0] = a0;
        op[f1] = a1;
        op[f2] = a2;
        if (lead) op[48] = a3;
    }
}

extern "C" void kernel_launch(void* const* d_in, const int* in_sizes, int n_in,
                              void* d_out, int out_size, void* d_ws, size_t ws_size,
                              hipStream_t stream) {
    const float* vid   = (const float*)d_in[0];
    const float* dists = (const float*)d_in[1];
    const int*   inds  = (const int*)d_in[2];
    float*       out   = (float*)d_out;

    dim3 grid(HD * C * CHUNKS);   // 256 blocks: (hd, c, chunk)
    dim3 block(BLOCK);            // 1024 threads = 64 pixel-groups of 16 lanes
    hipLaunchKernelGGL(wpsum_kernel, grid, block, 0, stream,
                       vid, dists, inds, out);
}

// Round 2
// 410.919 us; speedup vs baseline: 1.1709x; 1.1709x over previous
//
#include <hip/hip_runtime.h>

namespace {
constexpr int HD = 2;
constexpr int T  = 4;
constexpr int C  = 16;
constexpr int H  = 96;
constexpr int W  = 96;
constexpr int K  = 10;
constexpr int PS = 7;
constexpr int HW = H * W;              // 9216
constexpr int NPIX = T * HW;           // 36864 pixels per hd
constexpr int PATCH = PS * PS;         // 49
constexpr int OUTPIX = C * PATCH;      // 784 floats per pixel
constexpr int CHUNKS = 8;
constexpr int PIX_PER_CHUNK = NPIX / CHUNKS; // 4608
constexpr int BLOCK = 1024;
constexpr int GROUPS = BLOCK / 16;     // 64 pixel-groups per block
constexpr int ITERS = PIX_PER_CHUNK / GROUPS; // 72

// LDS row stride padded so consecutive patch rows start 8 banks apart
// (104 mod 32 = 8). With 16 lanes reading {f, f+16, f+32} patch elements,
// each group's 16 addresses land in 16 DISTINCT banks -> no intra-group
// conflict (W=96 gave 3-way: 96 mod 32 == 0).
constexpr int WS    = 104;             // padded row stride (floats)
constexpr int PLANE = H * WS;          // 9984 floats per t-plane
}

__global__ __launch_bounds__(BLOCK, 1)
void wpsum_kernel(const float* __restrict__ vid,
                  const float* __restrict__ dists,
                  const int* __restrict__ inds,
                  float* __restrict__ out)
{
    // vid[0, hd, :, c, :, :] staged with padded rows: 4*9984*4B = 156 KiB
    __shared__ float s_vid[T * PLANE];

    const int bid   = blockIdx.x;
    const int chunk = bid & (CHUNKS - 1);        // 8 chunks
    const int c     = (bid >> 3) & (C - 1);      // 16 channels
    const int hd    = bid >> 7;                  // 2 heads

    const int tid = threadIdx.x;

    // ---- stage the (hd, c) slice into LDS with row stride WS ----
    for (int t = 0; t < T; ++t) {
        const float* gsrc = vid + (size_t)((hd * T + t) * C + c) * HW;
        for (int idx = tid; idx < H * (W / 4); idx += BLOCK) {
            const int r = idx / (W / 4);
            const int q = idx % (W / 4);
            float4 v = reinterpret_cast<const float4*>(gsrc + r * W)[q];
            reinterpret_cast<float4*>(s_vid + t * PLANE + r * WS)[q] = v;
        }
    }
    __syncthreads();

    const int g = tid >> 4;        // pixel-group within block (0..63)
    const int l = tid & 15;        // lane within group

    // Each lane owns patch elements f0,f1,f2 (and lane 0 also f=48)
    const int f0 = l, f1 = l + 16, f2 = l + 32;
    const int i0 = f0 / 7, j0 = f0 % 7;
    const int i1 = f1 / 7, j1 = f1 % 7;
    const int i2 = f2 / 7, j2 = f2 % 7;
    const int w0 = i0 * WS + j0;
    const int w1 = i1 * WS + j1;
    const int w2 = i2 * WS + j2;
    constexpr int w3 = 6 * WS + 6;    // f = 48 -> (i=6, j=6)
    const bool lead = (l == 0);

    const float* dbase = dists + (size_t)hd * NPIX * K;
    const int*   ibase = inds  + (size_t)hd * NPIX * K * 3;
    float*       obase = out   + (size_t)hd * NPIX * OUTPIX + (size_t)c * PATCH;

    const int pix0 = chunk * PIX_PER_CHUNK + g;

    for (int itr = 0; itr < ITERS; ++itr) {
        const int p = pix0 + itr * GROUPS;

        // ---- hoist all per-pixel metadata via 8B-aligned wide loads ----
        // dists: p*10 floats -> 40B stride, 8B aligned. inds: p*30 ints, 8B aligned.
        float2 dv[5];
        const float2* dp2 = reinterpret_cast<const float2*>(dbase + (size_t)p * K);
#pragma unroll
        for (int q = 0; q < 5; ++q) dv[q] = dp2[q];
        int2 iv[15];
        const int2* ip2 = reinterpret_cast<const int2*>(ibase + (size_t)p * (K * 3));
#pragma unroll
        for (int q = 0; q < 15; ++q) iv[q] = ip2[q];

        const float* dvf = reinterpret_cast<const float*>(dv);
        const int*   ivi = reinterpret_cast<const int*>(iv);

        float a0 = 0.f, a1 = 0.f, a2 = 0.f, a3 = 0.f;

#pragma unroll
        for (int k = 0; k < K; ++k) {
            const float d  = dvf[k];            // compile-time index (full unroll)
            const int   tt = ivi[3 * k + 0];    // in [0,T): reflect(tt) == tt
            const int   ir = ivi[3 * k + 1];
            const int   ic = ivi[3 * k + 2];
            const int   tb = tt * PLANE;

            if (ir <= H - PS && ic <= W - PS) {
                // fast path: patch fully interior
                const int b0 = tb + ir * WS + ic;
                a0 += d * s_vid[b0 + w0];
                a1 += d * s_vid[b0 + w1];
                a2 += d * s_vid[b0 + w2];
                if (lead) a3 += d * s_vid[b0 + w3];
            } else {
                // slow path: reflect each coordinate (group-uniform branch)
                int rr, cc;
                rr = ir + i0; if (rr > H - 1) rr = 2 * (H - 1) - rr;
                cc = ic + j0; if (cc > W - 1) cc = 2 * (W - 1) - cc;
                a0 += d * s_vid[tb + rr * WS + cc];

                rr = ir + i1; if (rr > H - 1) rr = 2 * (H - 1) - rr;
                cc = ic + j1; if (cc > W - 1) cc = 2 * (W - 1) - cc;
                a1 += d * s_vid[tb + rr * WS + cc];

                rr = ir + i2; if (rr > H - 1) rr = 2 * (H - 1) - rr;
                cc = ic + j2; if (cc > W - 1) cc = 2 * (W - 1) - cc;
                a2 += d * s_vid[tb + rr * WS + cc];

                if (lead) {
                    rr = ir + 6; if (rr > H - 1) rr = 2 * (H - 1) - rr;
                    cc = ic + 6; if (cc > W - 1) cc = 2 * (W - 1) - cc;
                    a3 += d * s_vid[tb + rr * WS + cc];
                }
            }
        }

        float* op = obase + (size_t)p * OUTPIX;
        op[f0] = a0;
        op[f1] = a1;
        op[f2] = a2;
        if (lead) op[48] = a3;
    }
}

extern "C" void kernel_launch(void* const* d_in, const int* in_sizes, int n_in,
                              void* d_out, int out_size, void* d_ws, size_t ws_size,
                              hipStream_t stream) {
    const float* vid   = (const float*)d_in[0];
    const float* dists = (const float*)d_in[1];
    const int*   inds  = (const int*)d_in[2];
    float*       out   = (float*)d_out;

    dim3 grid(HD * C * CHUNKS);   // 256 blocks: (hd, c, chunk)
    dim3 block(BLOCK);            // 1024 threads = 64 pixel-groups of 16 lanes
    hipLaunchKernelGGL(wpsum_kernel, grid, block, 0, stream,
                       vid, dists, inds, out);
}

// Round 4
// 359.320 us; speedup vs baseline: 1.3391x; 1.1436x over previous
//
#include <hip/hip_runtime.h>

namespace {
constexpr int HD = 2;
constexpr int T  = 4;
constexpr int C  = 16;
constexpr int H  = 96;
constexpr int W  = 96;
constexpr int K  = 10;
constexpr int PS = 7;
constexpr int HW = H * W;              // 9216
constexpr int NPIX = T * HW;           // 36864 pixels per hd
constexpr int PATCH = PS * PS;         // 49
constexpr int OUTPIX = C * PATCH;      // 784 floats per pixel
constexpr int CHUNKS = 8;
constexpr int PIX_PER_CHUNK = NPIX / CHUNKS; // 4608
constexpr int BLOCK = 1024;
constexpr int GROUPS = BLOCK / 16;     // 64 pixel-groups per block
constexpr int ITERS = PIX_PER_CHUNK / GROUPS; // 72

// Plane layout: 96 rows x 102 cols. Cols 96..101 hold the reflected column
// halo (col 96+e = source col 94-e), so column reflection costs nothing in
// the k-loop. Stride 102 mod 32 = 6 -> each group's 16 LDS reads land in
// >=14 distinct banks (only free 2-way dups).
constexpr int WS    = 102;             // padded row stride (floats)
constexpr int PLANE = H * WS;          // 9792 floats per t-plane
constexpr int REFL  = 2 * (H - 1);     // 190: reflect(a) = min(a, 190-a)
}

__global__ __launch_bounds__(BLOCK, 1)
void wpsum_kernel(const float* __restrict__ vid,
                  const float* __restrict__ dists,
                  const int* __restrict__ inds,
                  float* __restrict__ out)
{
    // vid[0, hd, :, c, :, :] staged with col-halo: 4*9792*4B = 156.7 KiB
    __shared__ float s_vid[T * PLANE];

    const int bid   = blockIdx.x;
    const int chunk = bid & (CHUNKS - 1);        // 8 chunks
    const int c     = (bid >> 3) & (C - 1);      // 16 channels
    const int hd    = bid >> 7;                  // 2 heads

    const int tid = threadIdx.x;

    // ---- stage the (hd, c) slice into LDS (float2: rows are 8B-aligned) ----
    for (int t = 0; t < T; ++t) {
        const float* gsrc = vid + (size_t)((hd * T + t) * C + c) * HW;
        float*       dst  = s_vid + t * PLANE;
        for (int idx = tid; idx < H * (W / 2); idx += BLOCK) {
            const int r = idx / (W / 2);
            const int q = idx % (W / 2);
            float2 v = reinterpret_cast<const float2*>(gsrc + r * W)[q];
            reinterpret_cast<float2*>(dst + r * WS)[q] = v;
        }
        // column halo: col 96+e = source col 94-e  (96 rows x 6 cols)
        if (tid < H * (WS - W)) {
            const int r = tid / (WS - W);
            const int e = tid % (WS - W);
            dst[r * WS + W + e] = gsrc[r * W + (W - 2) - e];
        }
    }
    __syncthreads();

    const int g = tid >> 4;        // pixel-group within block (0..63)
    const int l = tid & 15;        // lane within group

    // Each lane owns patch elements f0,f1,f2 (and lane 0 also f=48)
    const int f0 = l, f1 = l + 16, f2 = l + 32;
    const int i0 = f0 / 7, j0 = f0 % 7;
    const int i1 = f1 / 7, j1 = f1 % 7;
    const int i2 = f2 / 7, j2 = f2 % 7;
    const int w0 = i0 * WS + j0;
    const int w1 = i1 * WS + j1;
    const int w2 = i2 * WS + j2;
    constexpr int w3 = 6 * WS + 6;    // f = 48 -> (i=6, j=6)
    const bool lead = (l == 0);

    const float* dbase = dists + (size_t)hd * NPIX * K;
    const int*   ibase = inds  + (size_t)hd * NPIX * K * 3;
    float*       obase = out   + (size_t)hd * NPIX * OUTPIX + (size_t)c * PATCH;

    const int pix0 = chunk * PIX_PER_CHUNK + g;

    for (int itr = 0; itr < ITERS; ++itr) {
        const int p = pix0 + itr * GROUPS;

        // ---- hoist all per-pixel metadata via 8B-aligned wide loads ----
        float2 dv[5];
        const float2* dp2 = reinterpret_cast<const float2*>(dbase + (size_t)p * K);
#pragma unroll
        for (int q = 0; q < 5; ++q) dv[q] = dp2[q];
        int2 iv[15];
        const int2* ip2 = reinterpret_cast<const int2*>(ibase + (size_t)p * (K * 3));
#pragma unroll
        for (int q = 0; q < 15; ++q) iv[q] = ip2[q];

        const float* dvf = reinterpret_cast<const float*>(dv);
        const int*   ivi = reinterpret_cast<const int*>(iv);

        float a0 = 0.f, a1 = 0.f, a2 = 0.f, a3 = 0.f;

#pragma unroll
        for (int k = 0; k < K; ++k) {
            const float d  = dvf[k];            // compile-time index (full unroll)
            const int   tt = ivi[3 * k + 0];    // in [0,T): reflect(tt) == tt
            const int   ir = ivi[3 * k + 1];
            const int   ic = ivi[3 * k + 2];
            // base = tt*PLANE + ic  (both mad24-able: all operands < 2^24)
            const int base = tt * PLANE + ic;

            if (!__any(ir > H - PS)) {
                // whole wave interior: cols covered by halo, rows direct
                const int b0 = base + ir * WS;
                a0 += d * s_vid[b0 + w0];
                a1 += d * s_vid[b0 + w1];
                a2 += d * s_vid[b0 + w2];
                if (lead) a3 += d * s_vid[b0 + w3];
            } else {
                // wave-uniform slow path: branchless row reflect,
                // correct for interior lanes too. Cols always via halo.
                const int m = REFL - ir;        // 190 - ir
                int rr;
                rr = min(ir + i0, m - i0);
                a0 += d * s_vid[base + rr * WS + j0];
                rr = min(ir + i1, m - i1);
                a1 += d * s_vid[base + rr * WS + j1];
                rr = min(ir + i2, m - i2);
                a2 += d * s_vid[base + rr * WS + j2];
                if (lead) {
                    rr = min(ir + 6, m - 6);
                    a3 += d * s_vid[base + rr * WS + 6];
                }
            }
        }

        float* op = obase + (size_t)p * OUTPIX;
        op[f0] = a0;
        op[f1] = a1;
        op[f2] = a2;
        if (lead) op[48] = a3;
    }
}

extern "C" void kernel_launch(void* const* d_in, const int* in_sizes, int n_in,
                              void* d_out, int out_size, void* d_ws, size_t ws_size,
                              hipStream_t stream) {
    const float* vid   = (const float*)d_in[0];
    const float* dists = (const float*)d_in[1];
    const int*   inds  = (const int*)d_in[2];
    float*       out   = (float*)d_out;

    dim3 grid(HD * C * CHUNKS);   // 256 blocks: (hd, c, chunk)
    dim3 block(BLOCK);            // 1024 threads = 64 pixel-groups of 16 lanes
    hipLaunchKernelGGL(wpsum_kernel, grid, block, 0, stream,
                       vid, dists, inds, out);
}

// Round 6
// 329.468 us; speedup vs baseline: 1.4604x; 1.0906x over previous
//
#include <hip/hip_runtime.h>
#include <hip/hip_fp16.h>

namespace {
constexpr int HD = 2;
constexpr int T  = 4;
constexpr int C  = 16;
constexpr int H  = 96;
constexpr int W  = 96;
constexpr int K  = 10;
constexpr int PS = 7;
constexpr int HW = H * W;              // 9216
constexpr int NPIX = T * HW;           // 36864 pixels per hd
constexpr int PATCH = PS * PS;         // 49
constexpr int OUTPIX = C * PATCH;      // 784 floats per pixel
constexpr int CHUNKS = 16;
constexpr int PIX_PER_CHUNK = NPIX / CHUNKS; // 2304
constexpr int BLOCK = 1024;
constexpr int GROUPS = BLOCK / 16;     // 64 pixel-groups per block
constexpr int ITERS = PIX_PER_CHUNK / GROUPS; // 36

// Dword layout: 96 rows x 104-dword stride. Each dword is a __half2 holding
// channels (c0, c1) at that position -> one ds_read_b32 + one v_pk_fma_f16
// serves TWO channels. Cols 96..101 hold the reflected column halo
// (col 96+e = source col 94-e). Stride 104 mod 32 = 8: all three per-group
// read patterns hit exactly 16 distinct banks (WS=102's mod-6 gave 2-way
// dups that stacked into the 3.2e7 conflicts measured in R4).
constexpr int WS    = 104;             // dword stride per row
constexpr int PLANE = H * WS;          // 9984 dwords per t-plane
constexpr int REFL  = 2 * (H - 1);     // 190: reflect(a) = min(a, 190-a)
}

__global__ __launch_bounds__(BLOCK, 1)
void wpsum_kernel(const float* __restrict__ vid,
                  const float* __restrict__ dists,
                  const int* __restrict__ inds,
                  float* __restrict__ out)
{
    // 4 * 9984 * 4B = 156 KiB (<= 160 KiB)
    __shared__ __half2 s_vid[T * PLANE];

    const int bid   = blockIdx.x;
    const int chunk = bid & (CHUNKS - 1);        // 16 pixel chunks
    const int cp    = (bid >> 4) & 7;            // 8 channel pairs
    const int hd    = bid >> 7;                  // 2 heads
    const int c0    = cp * 2;
    const int tid   = threadIdx.x;

    // ---- stage channel pair (c0, c0+1) as packed f16, with col halo ----
    for (int t = 0; t < T; ++t) {
        const float* g0 = vid + (size_t)((hd * T + t) * C + c0) * HW;
        const float* g1 = g0 + HW;
        __half2* dst = s_vid + t * PLANE;
        for (int idx = tid; idx < H * (W / 2); idx += BLOCK) {
            const int r = idx / (W / 2);
            const int q = idx % (W / 2);
            float2 v0 = reinterpret_cast<const float2*>(g0 + r * W)[q];
            float2 v1 = reinterpret_cast<const float2*>(g1 + r * W)[q];
            dst[r * WS + 2 * q]     = __floats2half2_rn(v0.x, v1.x);
            dst[r * WS + 2 * q + 1] = __floats2half2_rn(v0.y, v1.y);
        }
        // column halo: col 96+e = source col 94-e  (96 rows x 6 cols)
        if (tid < H * 6) {
            const int r = tid / 6;
            const int e = tid % 6;
            const int sc = r * W + (W - 2) - e;
            dst[r * WS + W + e] = __floats2half2_rn(g0[sc], g1[sc]);
        }
    }
    __syncthreads();

    const int g = tid >> 4;        // pixel-group within block (0..63)
    const int l = tid & 15;        // lane within group

    // Each lane owns patch elements f0,f1,f2 (lane 0 also f=48)
    const int f0 = l, f1 = l + 16, f2 = l + 32;
    const int i0 = f0 / 7, j0 = f0 % 7;
    const int i1 = f1 / 7, j1 = f1 % 7;
    const int i2 = f2 / 7, j2 = f2 % 7;
    const int w0 = i0 * WS + j0;
    const int w1 = i1 * WS + j1;
    const int w2 = i2 * WS + j2;
    constexpr int w3 = 6 * WS + 6;    // f = 48 -> (i=6, j=6)
    const bool lead = (l == 0);

    const float* dbase = dists + (size_t)hd * NPIX * K;
    const int*   ibase = inds  + (size_t)hd * NPIX * K * 3;
    float*       obase = out   + (size_t)hd * NPIX * OUTPIX + (size_t)c0 * PATCH;

    const int pix0 = chunk * PIX_PER_CHUNK + g;

    for (int itr = 0; itr < ITERS; ++itr) {
        const int p = pix0 + itr * GROUPS;

        // ---- hoist per-pixel metadata via 8B-aligned wide loads ----
        float2 dv[5];
        const float2* dp2 = reinterpret_cast<const float2*>(dbase + (size_t)p * K);
#pragma unroll
        for (int q = 0; q < 5; ++q) dv[q] = dp2[q];
        int2 iv[15];
        const int2* ip2 = reinterpret_cast<const int2*>(ibase + (size_t)p * (K * 3));
#pragma unroll
        for (int q = 0; q < 15; ++q) iv[q] = ip2[q];

        const float* dvf = reinterpret_cast<const float*>(dv);
        const int*   ivi = reinterpret_cast<const int*>(iv);

        // weights replicated into both f16 halves (compile-time indexed)
        __half2 dh[K];
#pragma unroll
        for (int k = 0; k < K; ++k) dh[k] = __float2half2_rn(dvf[k]);

        __half2 a0 = __float2half2_rn(0.f);
        __half2 a1 = a0, a2 = a0, a3 = a0;

#pragma unroll
        for (int k = 0; k < K; ++k) {
            const int tt = ivi[3 * k + 0];    // in [0,T): reflect == id
            const int ir = ivi[3 * k + 1];
            const int ic = ivi[3 * k + 2];
            const int base = tt * PLANE + ic;

            if (!__any(ir > H - PS)) {
                // whole wave interior: cols via halo, rows direct
                const int b0 = base + ir * WS;
                a0 = __hfma2(dh[k], s_vid[b0 + w0], a0);
                a1 = __hfma2(dh[k], s_vid[b0 + w1], a1);
                a2 = __hfma2(dh[k], s_vid[b0 + w2], a2);
                if (lead) a3 = __hfma2(dh[k], s_vid[b0 + w3], a3);
            } else {
                // wave-uniform slow path: branchless row reflect
                const int m = REFL - ir;        // 190 - ir
                int rr;
                rr = min(ir + i0, m - i0);
                a0 = __hfma2(dh[k], s_vid[base + rr * WS + j0], a0);
                rr = min(ir + i1, m - i1);
                a1 = __hfma2(dh[k], s_vid[base + rr * WS + j1], a1);
                rr = min(ir + i2, m - i2);
                a2 = __hfma2(dh[k], s_vid[base + rr * WS + j2], a2);
                if (lead) {
                    rr = min(ir + 6, m - 6);
                    a3 = __hfma2(dh[k], s_vid[base + rr * WS + 6], a3);
                }
            }
        }

        float* op = obase + (size_t)p * OUTPIX;
        const float2 r0 = __half22float2(a0);
        const float2 r1 = __half22float2(a1);
        const float2 r2 = __half22float2(a2);
        op[f0] = r0.x;  op[f0 + PATCH] = r0.y;
        op[f1] = r1.x;  op[f1 + PATCH] = r1.y;
        op[f2] = r2.x;  op[f2 + PATCH] = r2.y;
        if (lead) {
            const float2 r3 = __half22float2(a3);
            op[48] = r3.x;  op[48 + PATCH] = r3.y;
        }
    }
}

extern "C" void kernel_launch(void* const* d_in, const int* in_sizes, int n_in,
                              void* d_out, int out_size, void* d_ws, size_t ws_size,
                              hipStream_t stream) {
    const float* vid   = (const float*)d_in[0];
    const float* dists = (const float*)d_in[1];
    const int*   inds  = (const int*)d_in[2];
    float*       out   = (float*)d_out;

    dim3 grid(HD * (C / 2) * CHUNKS);  // 256 blocks: (hd, c-pair, chunk)
    dim3 block(BLOCK);                 // 64 pixel-groups of 16 lanes
    hipLaunchKernelGGL(wpsum_kernel, grid, block, 0, stream,
                       vid, dists, inds, out);
}